// Round 13
// baseline (204.828 us; speedup 1.0000x reference)
//
#include <hip/hip_runtime.h>
#include <hip/hip_bf16.h>

// Problem: B=2, S=2048, D=1024, H=16, dh=64. Inputs fp32, output FP32.
// Round 13:
//  - attn: 128-key stages (16 barrier pairs instead of 32)
//  - GEMM: BK=64 (16 stages), hsb/Wt stored chunk-XOR-swizzled so the
//    BK=64 frag reads stay bank-conflict-free (same pattern as K/V^T)
//  - round-half-up f2bf everywhere (2 inst, same 0.5-ulp bound)
// R12: 202 us total; attn3 79.7 us (MfmaUtil 17.6%), gemm chain ~122 us.

typedef __attribute__((ext_vector_type(8))) short bf16x8;
typedef __attribute__((ext_vector_type(4))) float f32x4;
typedef __attribute__((ext_vector_type(4))) int int4v;

#define MFMA16(A, B, C) __builtin_amdgcn_mfma_f32_16x16x32_bf16((A), (B), (C), 0, 0, 0)

#if __has_builtin(__builtin_amdgcn_exp2f)
#define EXP2(x) __builtin_amdgcn_exp2f(x)
#else
#define EXP2(x) exp2f(x)
#endif

static __device__ __forceinline__ unsigned short f2bf(float f) {
    union { float f; unsigned int u; } v;
    v.f = f;
    return (unsigned short)((v.u + 0x8000u) >> 16);   // round-half-up, 0.5 ulp
}

// async global->LDS DMA, 16B/lane; LDS dest = uniform base + lane*16
static __device__ __forceinline__ void gload_lds16(const void* g, void* l) {
    __builtin_amdgcn_global_load_lds(
        (const __attribute__((address_space(1))) void*)g,
        (__attribute__((address_space(3))) void*)l, 16, 0, 0);
}

// ---------------------------------------------------------------------------
// Pre-pass 1: cast hs fp32 -> bf16, stored with 8-elem chunk swizzle within
// each 64-elem k-group: chunk' = chunk ^ (m&7). (Consumed only by the GEMM.)
// ---------------------------------------------------------------------------
__global__ __launch_bounds__(256) void cast_hs(const float* __restrict__ in,
                                               unsigned short* __restrict__ out) {
    const size_t flat = ((size_t)blockIdx.x * 256 + threadIdx.x) * 8;
    const int m = (int)(flat >> 10);
    const int k = (int)(flat & 1023);
    float4 a0 = *reinterpret_cast<const float4*>(in + flat);
    float4 a1 = *reinterpret_cast<const float4*>(in + flat + 4);
    unsigned short t[8];
    t[0] = f2bf(a0.x); t[1] = f2bf(a0.y); t[2] = f2bf(a0.z); t[3] = f2bf(a0.w);
    t[4] = f2bf(a1.x); t[5] = f2bf(a1.y); t[6] = f2bf(a1.z); t[7] = f2bf(a1.w);
    const int csw = (((k >> 3) & 7) ^ (m & 7)) << 3;
    *reinterpret_cast<int4v*>(out + (size_t)m * 1024 + (k & ~63) + csw) =
        *reinterpret_cast<int4v*>(t);
}

// ---------------------------------------------------------------------------
// Pre-pass 2: W fp32 -> Wt[n][k] bf16, chunk-swizzled by (n&7) within each
// 64-elem k-group. 3 slices via grid.z.
// ---------------------------------------------------------------------------
__global__ __launch_bounds__(256) void transpose_cast_w(
    const float* __restrict__ W0, const float* __restrict__ W1,
    const float* __restrict__ W2, unsigned short* __restrict__ Wt) {
    __shared__ float Ts[64][65];
    const float* W = (blockIdx.z == 0) ? W0 : (blockIdx.z == 1) ? W1 : W2;
    unsigned short* O = Wt + (size_t)blockIdx.z * 1048576;

    const int t  = threadIdx.x;
    const int k0 = blockIdx.y * 64;
    const int n0 = blockIdx.x * 64;

    {
        const int kr = t >> 2, nc = (t & 3) * 16;
        const float* p = W + (size_t)(k0 + kr) * 1024 + n0 + nc;
        float4 r0 = *reinterpret_cast<const float4*>(p);
        float4 r1 = *reinterpret_cast<const float4*>(p + 4);
        float4 r2 = *reinterpret_cast<const float4*>(p + 8);
        float4 r3 = *reinterpret_cast<const float4*>(p + 12);
        float* d = &Ts[kr][nc];
        d[0]=r0.x; d[1]=r0.y; d[2]=r0.z; d[3]=r0.w;
        d[4]=r1.x; d[5]=r1.y; d[6]=r1.z; d[7]=r1.w;
        d[8]=r2.x; d[9]=r2.y; d[10]=r2.z; d[11]=r2.w;
        d[12]=r3.x; d[13]=r3.y; d[14]=r3.z; d[15]=r3.w;
    }
    __syncthreads();
    {
        const int nr = t >> 2, kc = (t & 3) * 16;   // kc in {0,16,32,48}
        unsigned short tmp[16];
#pragma unroll
        for (int i = 0; i < 16; i++) tmp[i] = f2bf(Ts[kc + i][nr]);
        unsigned short* base = O + (size_t)(n0 + nr) * 1024 + k0;
        const int c0 = ((kc >> 3) ^ (nr & 7)) & 7;
        const int c1 = (((kc >> 3) + 1) ^ (nr & 7)) & 7;
        *reinterpret_cast<int4v*>(base + c0 * 8) = *reinterpret_cast<int4v*>(&tmp[0]);
        *reinterpret_cast<int4v*>(base + c1 * 8) = *reinterpret_cast<int4v*>(&tmp[8]);
    }
}

// ---------------------------------------------------------------------------
// Kernel 3: QKV GEMM. 128x128 tile, BK=64 (16 stages), DMA staging from
// swizzled hsb/Wt; frag reads apply the matching XOR. 32 MFMA/stage.
// Epilogues: z=0 Q (pre-scaled 0.125*log2e), z=1 K (d-chunk^s&7),
//            z=2 V^T [B,H,dh,S] (s-chunk^d&7).
// ---------------------------------------------------------------------------
__global__ __launch_bounds__(256) void qkv_gemm_dma(
    const unsigned short* __restrict__ hsb,
    const unsigned short* __restrict__ Wt,
    const float* __restrict__ b0, const float* __restrict__ b1,
    const float* __restrict__ b2,
    unsigned short* __restrict__ Qo,
    unsigned short* __restrict__ Ko,
    unsigned short* __restrict__ Vto)
{
    __shared__ unsigned short As[128][64];   // [m][k] swizzled chunks
    __shared__ unsigned short Bs[128][64];   // [n][k] swizzled chunks

    const int z = blockIdx.z;
    const unsigned short* W = Wt + (size_t)z * 1048576;
    const float* bias = (z == 0) ? b0 : (z == 1) ? b1 : b2;

    const int tid  = threadIdx.x;
    const int lane = tid & 63;
    const int w    = tid >> 6;
    const int l15  = lane & 15;
    const int quad = lane >> 4;
    const int m0   = blockIdx.y * 128;
    const int n0   = blockIdx.x * 128;
    const int wm   = (w >> 1) * 64;
    const int wn   = (w & 1) * 64;

    const int drow = lane >> 3;          // 0..7 within 8-row DMA segment
    const int dcol = (lane & 7) * 8;

    f32x4 acc[4][4];
#pragma unroll
    for (int i = 0; i < 4; i++)
#pragma unroll
        for (int j = 0; j < 4; j++)
            acc[i][j] = (f32x4){0.f, 0.f, 0.f, 0.f};

    // swizzled chunk cols for frag reads: chunk = kk/8 + quad, key = l15&7
    const int l7 = l15 & 7;

    for (int k0 = 0; k0 < 1024; k0 += 64) {
        __syncthreads();
#pragma unroll
        for (int p = 0; p < 4; p++) {
            const int seg = w * 4 + p;           // 0..15, 8 rows each
            gload_lds16(hsb + (size_t)(m0 + seg * 8 + drow) * 1024 + k0 + dcol,
                        &As[seg * 8][0]);
            gload_lds16(W   + (size_t)(n0 + seg * 8 + drow) * 1024 + k0 + dcol,
                        &Bs[seg * 8][0]);
        }
        __syncthreads();

#pragma unroll
        for (int kk = 0; kk < 64; kk += 32) {
            const int csw = ((((kk >> 3) + quad) ^ l7) & 7) * 8;
            bf16x8 af[4], bfr[4];
#pragma unroll
            for (int i = 0; i < 4; i++)
                af[i] = *reinterpret_cast<const bf16x8*>(&As[wm + i * 16 + l15][csw]);
#pragma unroll
            for (int j = 0; j < 4; j++)
                bfr[j] = *reinterpret_cast<const bf16x8*>(&Bs[wn + j * 16 + l15][csw]);
#pragma unroll
            for (int i = 0; i < 4; i++)
#pragma unroll
                for (int j = 0; j < 4; j++)
                    acc[i][j] = MFMA16(af[i], bfr[j], acc[i][j]);
        }
    }

    if (z == 0) {
        const float qs = 0.18033688f;   // 0.125 * log2(e)
#pragma unroll
        for (int i = 0; i < 4; i++) {
            const int mbase = m0 + wm + i * 16 + quad * 4;
#pragma unroll
            for (int j = 0; j < 4; j++) {
                const int n = n0 + wn + j * 16 + l15;
                const int h = n >> 6, d = n & 63;
                const float bn = bias[n];
#pragma unroll
                for (int r = 0; r < 4; r++) {
                    const int mm = mbase + r;
                    const int b = mm >> 11, s = mm & 2047;
                    Qo[(((size_t)(b * 16 + h) * 2048 + s) * 64) + d] =
                        f2bf((acc[i][j][r] + bn) * qs);
                }
            }
        }
    } else if (z == 1) {
#pragma unroll
        for (int i = 0; i < 4; i++) {
            const int mbase = m0 + wm + i * 16 + quad * 4;
#pragma unroll
            for (int j = 0; j < 4; j++) {
                const int n = n0 + wn + j * 16 + l15;
                const int h = n >> 6, d = n & 63;
                const float bn = bias[n];
#pragma unroll
                for (int r = 0; r < 4; r++) {
                    const int mm = mbase + r;
                    const int b = mm >> 11, s = mm & 2047;
                    const int dsw = ((((d >> 3) ^ (s & 7)) & 7) << 3) | (d & 7);
                    Ko[(((size_t)(b * 16 + h) * 2048 + s) * 64) + dsw] =
                        f2bf(acc[i][j][r] + bn);
                }
            }
        }
    } else {
#pragma unroll
        for (int i = 0; i < 4; i++) {
            const int mbase = m0 + wm + i * 16 + quad * 4;
            const int b = mbase >> 11, s0 = mbase & 2047;
#pragma unroll
            for (int j = 0; j < 4; j++) {
                const int n = n0 + wn + j * 16 + l15;
                const int h = n >> 6, d = n & 63;
                const float bn = bias[n];
                ushort4 v4;
                v4.x = f2bf(acc[i][j][0] + bn);
                v4.y = f2bf(acc[i][j][1] + bn);
                v4.z = f2bf(acc[i][j][2] + bn);
                v4.w = f2bf(acc[i][j][3] + bn);
                const int cs  = (s0 & 63) >> 3;
                const int ssw = (s0 & ~63) | (((cs ^ (d & 7)) & 7) << 3) | (s0 & 7);
                *reinterpret_cast<ushort4*>(
                    Vto + ((size_t)(b * 16 + h) * 64 + d) * 2048 + ssw) = v4;
            }
        }
    }
}

// ---------------------------------------------------------------------------
// Kernel 4: MFMA flash attention, max-free softmax, 128-key stages.
// 1 block = (b,h,64 q-rows), 4 waves; wave w owns q-rows [16w,16w+16).
// ---------------------------------------------------------------------------
__global__ __launch_bounds__(256) void attn4(
    const unsigned short* __restrict__ Qg,
    const unsigned short* __restrict__ Kg,
    const unsigned short* __restrict__ Vtg,
    float* __restrict__ out)
{
    __shared__ unsigned short Ks[128][64];     // [kk][d] swizzled (DMA)
    __shared__ unsigned short Vs[64][128];     // V^T [d][kk] swizzled (DMA)
    __shared__ unsigned short Ps[4][16][66];   // per-wave P [qrow][kk0..63]

    const int tid  = threadIdx.x;
    const int lane = tid & 63;
    const int w    = tid >> 6;
    const int l15  = lane & 15;
    const int quad = lane >> 4;

    const int q0 = blockIdx.x * 64;
    const int h  = blockIdx.y;
    const int b  = blockIdx.z;
    const size_t base = (size_t)(b * 16 + h) * 2048 * 64;
    const unsigned short* Qh  = Qg  + base;
    const unsigned short* Kh  = Kg  + base;
    const unsigned short* Vth = Vtg + base;

    bf16x8 qf[2];
#pragma unroll
    for (int ks = 0; ks < 2; ks++)
        qf[ks] = *reinterpret_cast<const bf16x8*>(
            Qh + (size_t)(q0 + w * 16 + l15) * 64 + ks * 32 + quad * 8);

    f32x4 o[4];
#pragma unroll
    for (int t = 0; t < 4; t++) o[t] = (f32x4){0.f, 0.f, 0.f, 0.f};
    float rsum[4] = {0.f, 0.f, 0.f, 0.f};

    const int c0 = (((quad + 0) ^ (l15 & 7)) & 7) * 8;   // ks=0 swizzled col
    const int c1 = (((quad + 4) ^ (l15 & 7)) & 7) * 8;   // ks=1

    for (int kt = 0; kt < 16; kt++) {
        __syncthreads();
        // K: 128x64 = 16 KB = 16 wave-DMAs (4/thread)
#pragma unroll
        for (int p = 0; p < 4; p++) {
            const int seg = w * 4 + p;   // 8 rows each
            gload_lds16(Kh + (size_t)kt * 8192 +
                            (size_t)(seg * 8 + (lane >> 3)) * 64 + (lane & 7) * 8,
                        &Ks[seg * 8][0]);
            // V: rows of 128 shorts (256B); 4 rows per wave-DMA
            gload_lds16(Vth + (size_t)(seg * 4 + (lane >> 4)) * 2048 +
                            kt * 128 + (lane & 15) * 8,
                        &Vs[seg * 4][0]);
        }
        __syncthreads();

#pragma unroll
        for (int u = 0; u < 2; u++) {
            // S = Q~ K^T ; P = exp2(S)
#pragma unroll
            for (int t = 0; t < 4; t++) {
                f32x4 sc = (f32x4){0.f, 0.f, 0.f, 0.f};
                {
                    bf16x8 kf = *reinterpret_cast<const bf16x8*>(
                        &Ks[u * 64 + t * 16 + l15][c0]);
                    sc = MFMA16(qf[0], kf, sc);
                }
                {
                    bf16x8 kf = *reinterpret_cast<const bf16x8*>(
                        &Ks[u * 64 + t * 16 + l15][c1]);
                    sc = MFMA16(qf[1], kf, sc);
                }
#pragma unroll
                for (int r = 0; r < 4; r++) {
                    const float p = EXP2(sc[r]);
                    rsum[r] += p;
                    Ps[w][quad * 4 + r][t * 16 + l15] = f2bf(p);
                }
            }

            __builtin_amdgcn_wave_barrier();   // Ps wave-private: order W->R

            bf16x8 pf[2];
#pragma unroll
            for (int ks = 0; ks < 2; ks++)
                pf[ks] = *reinterpret_cast<const bf16x8*>(
                    &Ps[w][l15][ks * 32 + quad * 8]);
#pragma unroll
            for (int t = 0; t < 4; t++) {
                {
                    bf16x8 vf = *reinterpret_cast<const bf16x8*>(
                        &Vs[t * 16 + l15][u * 64 + c0]);
                    o[t] = MFMA16(pf[0], vf, o[t]);
                }
                {
                    bf16x8 vf = *reinterpret_cast<const bf16x8*>(
                        &Vs[t * 16 + l15][u * 64 + c1]);
                    o[t] = MFMA16(pf[1], vf, o[t]);
                }
            }
            __builtin_amdgcn_wave_barrier();   // order R before next-u W
        }
    }

    // deferred l reduction
#pragma unroll
    for (int off = 1; off < 16; off <<= 1)
#pragma unroll
        for (int r = 0; r < 4; r++)
            rsum[r] += __shfl_xor(rsum[r], off, 64);

#pragma unroll
    for (int t = 0; t < 4; t++) {
#pragma unroll
        for (int r = 0; r < 4; r++) {
            const int q = q0 + w * 16 + quad * 4 + r;
            const size_t oidx = (((size_t)b * 2048 + q) * 16 + h) * 64 + t * 16 + l15;
            out[oidx] = o[t][r] / rsum[r];
        }
    }
}

// ---------------------------------------------------------------------------
__global__ void fill_sentinel(float* out, int n, float pat) {
    int i = blockIdx.x * blockDim.x + threadIdx.x;
    if (i < n) out[i] = pat;
}

// ---------------------------------------------------------------------------
extern "C" void kernel_launch(void* const* d_in, const int* in_sizes, int n_in,
                              void* d_out, int out_size, void* d_ws, size_t ws_size,
                              hipStream_t stream) {
    const size_t n_hs  = (size_t)4096 * 1024;
    const size_t n_w   = (size_t)1024 * 1024;
    const size_t n_qkv = n_hs;
    const size_t need = (n_hs + 3 * n_w + 3 * n_qkv) * sizeof(unsigned short);

    bool order_ok = (n_in == 7) &&
        in_sizes[0] == 4194304 &&
        in_sizes[1] == 1048576 && in_sizes[2] == 1024 &&
        in_sizes[3] == 1048576 && in_sizes[4] == 1024 &&
        in_sizes[5] == 1048576 && in_sizes[6] == 1024;
    if (!order_ok || out_size != 4194304) {
        fill_sentinel<<<(out_size + 255) / 256, 256, 0, stream>>>(
            (float*)d_out, out_size, 4.0f);
        return;
    }
    if (ws_size < need) {
        fill_sentinel<<<(out_size + 255) / 256, 256, 0, stream>>>(
            (float*)d_out, out_size, 2.0f);
        return;
    }

    const float* hs = (const float*)d_in[0];
    const float* Wq = (const float*)d_in[1];
    const float* bq = (const float*)d_in[2];
    const float* Wk = (const float*)d_in[3];
    const float* bk = (const float*)d_in[4];
    const float* Wv = (const float*)d_in[5];
    const float* bv = (const float*)d_in[6];

    unsigned short* hsb = (unsigned short*)d_ws;
    unsigned short* Wt  = hsb + n_hs;
    unsigned short* Q   = Wt + 3 * n_w;
    unsigned short* K   = Q + n_qkv;
    unsigned short* Vt  = K + n_qkv;

    cast_hs<<<2048, 256, 0, stream>>>(hs, hsb);
    transpose_cast_w<<<dim3(16, 16, 3), 256, 0, stream>>>(Wq, Wk, Wv, Wt);

    dim3 g1(8, 32, 3);    // (N/128, M/128, {q,k,v})
    qkv_gemm_dma<<<g1, dim3(256), 0, stream>>>(hsb, Wt, bq, bk, bv, Q, K, Vt);

    dim3 g2(32, 16, 2);   // (S/64, H, B)
    attn4<<<g2, dim3(256), 0, stream>>>(Q, K, Vt, (float*)d_out);
}